// Round 7
// baseline (302.424 us; speedup 1.0000x reference)
//
#include <hip/hip_runtime.h>

// GatedCrossModalAttention: B=16384, NM=5, D=256. FP32 I/O, bf16 internal.
// Attention collapses (Lq=Lk=1): branch_s(x) = x[:,mod_s] @ (Wo_s@Wv_s)^T + (Wo_s@bv_s+bo_s).
// R6 lessons: k_main is per-block-latency-bound (time ~ block count; WF re-read per block);
//             k_fuse's 256-iter stride-1KB loop was ~135us (no load pipelining) -> MFMA rewrite.
// R5 lesson: gates must be fp32. R2 lesson: keep ws small (WF 640KB + BF 5KB only).

typedef __attribute__((ext_vector_type(8))) short short8;
typedef __attribute__((ext_vector_type(4))) float floatx4;

__device__ __forceinline__ float b2f(unsigned short h){ return __uint_as_float((unsigned)h << 16); }
__device__ __forceinline__ unsigned short f2b(float f){
    unsigned u = __float_as_uint(f);
    return (unsigned short)((u + 0x7FFFu + ((u >> 16) & 1u)) >> 16);
}
template<int CTRL>
__device__ __forceinline__ float dpp_add(float v){
    int x = __builtin_amdgcn_update_dpp(0, __float_as_int(v), CTRL, 0xf, 0xf, true);
    return v + __int_as_float(x);
}
// sum across 64 lanes, broadcast via readlane 63 (VALU pipe only)
__device__ __forceinline__ float wsum(float v){
    v = dpp_add<0x111>(v); v = dpp_add<0x112>(v); v = dpp_add<0x114>(v);
    v = dpp_add<0x118>(v); v = dpp_add<0x142>(v); v = dpp_add<0x143>(v);
    return __int_as_float(__builtin_amdgcn_readlane(__float_as_int(v), 63));
}
__device__ __forceinline__ short8 pack8(float4 a, float4 b){
    short8 r;
    r[0]=(short)f2b(a.x); r[1]=(short)f2b(a.y); r[2]=(short)f2b(a.z); r[3]=(short)f2b(a.w);
    r[4]=(short)f2b(b.x); r[5]=(short)f2b(b.y); r[6]=(short)f2b(b.z); r[7]=(short)f2b(b.w);
    return r;
}

// ---------------- K1: weight fusion via MFMA ----------------
// grid (2,5), block 256 (4 waves). Block: WF_s[:, j0:j0+128] = Wo_s @ Wv_s (columns j0..j0+127).
// Wv^T staged in LDS bf16 with XOR swizzle: VT(j,k) at hw j*256 + ((kb^(j&31))<<3) + (k&7), kb=k>>3.
// Wave w: output rows [w*64, w*64+64). A-frags (Wo) read from global fp32 + packed.
__global__ __launch_bounds__(256) void k_fuse(
    const float* __restrict__ sWi, const float* __restrict__ sbi,
    const float* __restrict__ sWo, const float* __restrict__ sbo,
    const float* __restrict__ cWi, const float* __restrict__ cbi,
    const float* __restrict__ cWo, const float* __restrict__ cbo,
    unsigned short* __restrict__ WF, float* __restrict__ BF)
{
    int s = blockIdx.y;
    int j0 = blockIdx.x * 128;
    int tid = threadIdx.x;
    int wave = tid >> 6, lane = tid & 63;
    int l16 = lane & 15, q4 = lane >> 4;
    const float *Wo, *Wv, *bv, *bo;
    if (s == 0) { Wo = sWo; Wv = sWi + 512 * 256; bv = sbi + 512; bo = sbo; }
    else {
        int n = s - 1;
        Wo = cWo + n * 65536;
        Wv = cWi + n * 768 * 256 + 512 * 256;
        bv = cbi + n * 768 + 512;
        bo = cbo + n * 256;
    }
    __shared__ __align__(16) unsigned short VT[128 * 256];  // 64 KB

    // stage Wv^T (coalesced fp32 reads, swizzled bf16 writes)
    #pragma unroll 8
    for (int it = 0; it < 128; ++it) {
        int idx = tid + it * 256;
        int jl = idx & 127;
        int k = idx >> 7;
        float v = Wv[k * 256 + j0 + jl];
        int kb = k >> 3, k7 = k & 7;
        VT[jl * 256 + ((kb ^ (jl & 31)) << 3) + k7] = f2b(v);
    }
    __syncthreads();

    floatx4 acc[4][8];
    #pragma unroll
    for (int rt = 0; rt < 4; ++rt)
        #pragma unroll
        for (int ct = 0; ct < 8; ++ct) acc[rt][ct] = (floatx4){0.f,0.f,0.f,0.f};

    #pragma unroll
    for (int kk = 0; kk < 8; ++kk) {
        short8 af[4];
        #pragma unroll
        for (int rt = 0; rt < 4; ++rt) {
            int i = wave * 64 + rt * 16 + l16;
            const float* p = Wo + (size_t)i * 256 + kk * 32 + q4 * 8;
            float4 f0 = *(const float4*)p;
            float4 f1 = *(const float4*)(p + 4);
            af[rt] = pack8(f0, f1);
        }
        #pragma unroll
        for (int ct = 0; ct < 8; ++ct) {
            int jl = ct * 16 + l16;
            int kb = kk * 4 + q4;
            short8 bf = *(const short8*)(VT + jl * 256 + ((kb ^ (jl & 31)) << 3));
            #pragma unroll
            for (int rt = 0; rt < 4; ++rt)
                acc[rt][ct] = __builtin_amdgcn_mfma_f32_16x16x32_bf16(af[rt], bf, acc[rt][ct], 0, 0, 0);
        }
    }
    // store C: row=(lane>>4)*4+reg, col=lane&15 within each 16x16 tile
    #pragma unroll
    for (int rt = 0; rt < 4; ++rt)
        #pragma unroll
        for (int ct = 0; ct < 8; ++ct)
            #pragma unroll
            for (int reg = 0; reg < 4; ++reg) {
                int i = wave * 64 + rt * 16 + q4 * 4 + reg;
                int j = j0 + ct * 16 + l16;
                WF[((size_t)s * 256 + i) * 256 + j] = f2b(acc[rt][ct][reg]);
            }
    // bias (only j0==0 blocks): BF[s][r] = Wo[r,:].bv + bo[r]
    if (j0 == 0) {
        float4 bvv = *(const float4*)(bv + lane * 4);
        for (int r8 = 0; r8 < 64; ++r8) {
            int r = wave * 64 + r8;
            float4 w4 = *(const float4*)(Wo + (size_t)r * 256 + lane * 4);
            float p = w4.x * bvv.x + w4.y * bvv.y + w4.z * bvv.z + w4.w * bvv.w;
            p = wsum(p);
            if (lane == 0) BF[s * 256 + r] = p + bo[r];
        }
    }
}

// ---------------- K2: fused GEMM + epilogue ----------------
// grid 512, block 256 (4 waves), 32 rows/block. Double-buffered A (swizzled bf16):
//   A_hw(row,k) = ((g*32 + kb)*16 + ((row&15) ^ (kb&15)))*8 + (k&7), g=row>>4, kb=k>>3.
// Wave w: GEMM cols [w*64,+64) (acc[2][4]); epilogue rows [w*8,+8).
__global__ __launch_bounds__(256, 3) void k_main(
    const float* __restrict__ x, const unsigned short* __restrict__ WF,
    const float* __restrict__ BF,
    const float* __restrict__ cln_g, const float* __restrict__ cln_b,
    const float* __restrict__ gln_g, const float* __restrict__ gln_b,
    const float* __restrict__ gW, const float* __restrict__ gb,
    const float* __restrict__ fln_g, const float* __restrict__ fln_b,
    const int* __restrict__ midx, float* __restrict__ out)
{
    __shared__ __align__(16) unsigned short A[2][8192];    // 2 x 16 KB
    __shared__ __align__(16) unsigned short Yb[32 * 264];  // 16.9 KB
    __shared__ float gLDS[32 * 5];

    int m = midx[0];
    int b0 = blockIdx.x * 32;
    int tid = threadIdx.x;
    int wave = tid >> 6, lane = tid & 63;
    int l16 = lane & 15, q4 = lane >> 4;

    int mods[5];
    mods[0] = m;
    #pragma unroll
    for (int s = 1; s < 5; ++s) mods[s] = (s - 1 < m) ? s - 1 : s;

    // q rows (fp32) for this wave's 8 epilogue rows
    float4 qv[8];
    #pragma unroll
    for (int rr = 0; rr < 8; ++rr)
        qv[rr] = *(const float4*)(x + ((size_t)(b0 + wave * 8 + rr) * 5 + m) * 256 + lane * 4);

    // stage branch 0 into A[0]
    float4 st[8];
    #pragma unroll
    for (int it = 0; it < 8; ++it) {
        int idx = tid + it * 256;
        int row = idx >> 6, c4 = (idx & 63) << 2;
        st[it] = *(const float4*)(x + ((size_t)(b0 + row) * 5 + mods[0]) * 256 + c4);
    }
    #pragma unroll
    for (int it = 0; it < 8; ++it) {
        int idx = tid + it * 256;
        int row = idx >> 6, c4 = (idx & 63) << 2;
        int g = row >> 4, r16 = row & 15, kb = c4 >> 3, k7 = c4 & 7;
        uint2 p;
        p.x = (unsigned)f2b(st[it].x) | ((unsigned)f2b(st[it].y) << 16);
        p.y = (unsigned)f2b(st[it].z) | ((unsigned)f2b(st[it].w) << 16);
        *(uint2*)(A[0] + ((g * 32 + kb) * 16 + (r16 ^ (kb & 15))) * 8 + k7) = p;
    }

    // gates (fp32; R5 lesson) -> gLDS (same wave writes & reads its rows)
    {
        float4 glg = *(const float4*)(gln_g + lane * 4);
        float4 glb = *(const float4*)(gln_b + lane * 4);
        float4 gwv[5]; float gbv[5];
        #pragma unroll
        for (int n = 0; n < 5; ++n) {
            gwv[n] = *(const float4*)(gW + n * 256 + lane * 4);
            gbv[n] = gb[n];
        }
        #pragma unroll
        for (int rr = 0; rr < 8; ++rr) {
            int row = wave * 8 + rr;
            float s1 = wsum(qv[rr].x + qv[rr].y + qv[rr].z + qv[rr].w);
            float s2 = wsum(qv[rr].x*qv[rr].x + qv[rr].y*qv[rr].y + qv[rr].z*qv[rr].z + qv[rr].w*qv[rr].w);
            float mn = s1 * (1.f / 256.f);
            float vr = s2 * (1.f / 256.f) - mn * mn;
            float rs = rsqrtf(vr + 1e-5f);
            float q0 = (qv[rr].x - mn) * rs * glg.x + glb.x;
            float q1 = (qv[rr].y - mn) * rs * glg.y + glb.y;
            float q2 = (qv[rr].z - mn) * rs * glg.z + glb.z;
            float q3 = (qv[rr].w - mn) * rs * glg.w + glb.w;
            float lg[5];
            #pragma unroll
            for (int n = 0; n < 5; ++n) {
                float p = q0 * gwv[n].x + q1 * gwv[n].y + q2 * gwv[n].z + q3 * gwv[n].w;
                lg[n] = wsum(p) + gbv[n];
            }
            float mx = lg[0];
            #pragma unroll
            for (int n = 1; n < 5; ++n) mx = fmaxf(mx, lg[n]);
            float es = 0.f;
            #pragma unroll
            for (int n = 0; n < 5; ++n) { lg[n] = __expf(lg[n] - mx); es += lg[n]; }
            float inv = 1.f / es;
            if (lane == 0) {
                #pragma unroll
                for (int n = 0; n < 5; ++n) gLDS[row * 5 + n] = lg[n] * inv;
            }
        }
    }

    float comb[8][4];
    #pragma unroll
    for (int rr = 0; rr < 8; ++rr)
        #pragma unroll
        for (int i = 0; i < 4; ++i) comb[rr][i] = 0.f;

    __syncthreads();  // A[0] ready

    for (int s = 0; s < 5; ++s) {
        int cur = s & 1, nxt = cur ^ 1;
        // prefetch next branch (overlaps GEMM)
        if (s < 4) {
            int nmod = mods[s + 1];
            #pragma unroll
            for (int it = 0; it < 8; ++it) {
                int idx = tid + it * 256;
                int row = idx >> 6, c4 = (idx & 63) << 2;
                st[it] = *(const float4*)(x + ((size_t)(b0 + row) * 5 + nmod) * 256 + c4);
            }
        }
        // GEMM: 32 x 256, wave cols [wave*64,+64)
        floatx4 acc[2][4];
        #pragma unroll
        for (int rt = 0; rt < 2; ++rt)
            #pragma unroll
            for (int ct = 0; ct < 4; ++ct) acc[rt][ct] = (floatx4){0.f,0.f,0.f,0.f};
        const unsigned short* wB = WF + (size_t)s * 65536;
        #pragma unroll
        for (int kk = 0; kk < 8; ++kk) {
            int kb = kk * 4 + q4;
            short8 a0 = *(const short8*)(A[cur] + ((0 * 32 + kb) * 16 + (l16 ^ (kb & 15))) * 8);
            short8 a1 = *(const short8*)(A[cur] + ((1 * 32 + kb) * 16 + (l16 ^ (kb & 15))) * 8);
            short8 bb[4];
            #pragma unroll
            for (int ct = 0; ct < 4; ++ct)
                bb[ct] = *(const short8*)(wB + (size_t)(wave * 64 + ct * 16 + l16) * 256 + kk * 32 + q4 * 8);
            #pragma unroll
            for (int ct = 0; ct < 4; ++ct) {
                acc[0][ct] = __builtin_amdgcn_mfma_f32_16x16x32_bf16(a0, bb[ct], acc[0][ct], 0, 0, 0);
                acc[1][ct] = __builtin_amdgcn_mfma_f32_16x16x32_bf16(a1, bb[ct], acc[1][ct], 0, 0, 0);
            }
        }
        // park Yb
        #pragma unroll
        for (int rt = 0; rt < 2; ++rt)
            #pragma unroll
            for (int i = 0; i < 4; ++i) {
                int r = rt * 16 + q4 * 4 + i;
                #pragma unroll
                for (int ct = 0; ct < 4; ++ct)
                    Yb[r * 264 + wave * 64 + ct * 16 + l16] = f2b(acc[rt][ct][i]);
            }
        // write prefetched tile into other buffer
        if (s < 4) {
            #pragma unroll
            for (int it = 0; it < 8; ++it) {
                int idx = tid + it * 256;
                int row = idx >> 6, c4 = (idx & 63) << 2;
                int g = row >> 4, r16 = row & 15, kb = c4 >> 3, k7 = c4 & 7;
                uint2 p;
                p.x = (unsigned)f2b(st[it].x) | ((unsigned)f2b(st[it].y) << 16);
                p.y = (unsigned)f2b(st[it].z) | ((unsigned)f2b(st[it].w) << 16);
                *(uint2*)(A[nxt] + ((g * 32 + kb) * 16 + (r16 ^ (kb & 15))) * 8 + k7) = p;
            }
        }
        __syncthreads();  // Yb ready (and A[nxt] complete)

        // epilogue: comb += g_s * (s==0 ? y : LN(q+y)) for rows wave*8..+7
        float4 bfv = *(const float4*)(BF + s * 256 + lane * 4);
        if (s == 0) {
            #pragma unroll
            for (int rr = 0; rr < 8; ++rr) {
                int row = wave * 8 + rr;
                uint2 u = *(const uint2*)(Yb + row * 264 + lane * 4);
                float g0 = gLDS[row * 5 + 0];
                comb[rr][0] += g0 * (b2f(u.x & 0xffff) + bfv.x);
                comb[rr][1] += g0 * (b2f(u.x >> 16) + bfv.y);
                comb[rr][2] += g0 * (b2f(u.y & 0xffff) + bfv.z);
                comb[rr][3] += g0 * (b2f(u.y >> 16) + bfv.w);
            }
        } else {
            float4 cg = *(const float4*)(cln_g + (s - 1) * 256 + lane * 4);
            float4 cb = *(const float4*)(cln_b + (s - 1) * 256 + lane * 4);
            #pragma unroll
            for (int rr = 0; rr < 8; ++rr) {
                int row = wave * 8 + rr;
                uint2 u = *(const uint2*)(Yb + row * 264 + lane * 4);
                float t0 = qv[rr].x + b2f(u.x & 0xffff) + bfv.x;
                float t1 = qv[rr].y + b2f(u.x >> 16) + bfv.y;
                float t2 = qv[rr].z + b2f(u.y & 0xffff) + bfv.z;
                float t3 = qv[rr].w + b2f(u.y >> 16) + bfv.w;
                float s1 = wsum(t0 + t1 + t2 + t3);
                float s2 = wsum(t0*t0 + t1*t1 + t2*t2 + t3*t3);
                float mn = s1 * (1.f / 256.f);
                float vr = s2 * (1.f / 256.f) - mn * mn;
                float rs = rsqrtf(vr + 1e-5f);
                float gs = gLDS[row * 5 + s];
                comb[rr][0] += gs * ((t0 - mn) * rs * cg.x + cb.x);
                comb[rr][1] += gs * ((t1 - mn) * rs * cg.y + cb.y);
                comb[rr][2] += gs * ((t2 - mn) * rs * cg.z + cb.z);
                comb[rr][3] += gs * ((t3 - mn) * rs * cg.w + cb.w);
            }
        }
        __syncthreads();  // Yb consumed before next park
    }

    // final LN + store
    float4 fg = *(const float4*)(fln_g + lane * 4);
    float4 fb = *(const float4*)(fln_b + lane * 4);
    #pragma unroll
    for (int rr = 0; rr < 8; ++rr) {
        int row = wave * 8 + rr;
        float t0 = qv[rr].x + comb[rr][0];
        float t1 = qv[rr].y + comb[rr][1];
        float t2 = qv[rr].z + comb[rr][2];
        float t3 = qv[rr].w + comb[rr][3];
        float s1 = wsum(t0 + t1 + t2 + t3);
        float s2 = wsum(t0*t0 + t1*t1 + t2*t2 + t3*t3);
        float mn = s1 * (1.f / 256.f);
        float vr = s2 * (1.f / 256.f) - mn * mn;
        float rs = rsqrtf(vr + 1e-5f);
        float4 ov;
        ov.x = (t0 - mn) * rs * fg.x + fb.x;
        ov.y = (t1 - mn) * rs * fg.y + fb.y;
        ov.z = (t2 - mn) * rs * fg.z + fb.z;
        ov.w = (t3 - mn) * rs * fg.w + fb.w;
        *(float4*)(out + (size_t)(b0 + row) * 256 + lane * 4) = ov;
    }
}

extern "C" void kernel_launch(void* const* d_in, const int* in_sizes, int n_in,
                              void* d_out, int out_size, void* d_ws, size_t ws_size,
                              hipStream_t stream) {
    const float* x    = (const float*)d_in[0];
    const float* sWi  = (const float*)d_in[1];
    const float* sbi  = (const float*)d_in[2];
    const float* sWo  = (const float*)d_in[3];
    const float* sbo  = (const float*)d_in[4];
    const float* cWi  = (const float*)d_in[5];
    const float* cbi  = (const float*)d_in[6];
    const float* cWo  = (const float*)d_in[7];
    const float* cbo  = (const float*)d_in[8];
    const float* clng = (const float*)d_in[9];
    const float* clnb = (const float*)d_in[10];
    const float* glng = (const float*)d_in[11];
    const float* glnb = (const float*)d_in[12];
    const float* gW   = (const float*)d_in[13];
    const float* gb   = (const float*)d_in[14];
    const float* flng = (const float*)d_in[15];
    const float* flnb = (const float*)d_in[16];
    const int* midx   = (const int*)d_in[17];
    float* out        = (float*)d_out;

    char* ws = (char*)d_ws;
    unsigned short* WF = (unsigned short*)ws;           // 655360 B
    float* BF          = (float*)(ws + 655360);         // 5120 B

    k_fuse<<<dim3(2, 5), 256, 0, stream>>>(sWi, sbi, sWo, sbo, cWi, cbi, cWo, cbo, WF, BF);
    k_main<<<512, 256, 0, stream>>>(x, WF, BF, clng, clnb, glng, glnb, gW, gb, flng, flnb, midx, out);
}